// Round 11
// baseline (50.042 us; speedup 1.0000x reference)
//
#include <hip/hip_runtime.h>

#define NB 128
#define NQ 1000
#define NG 300
#define NK 4
#define THRESH 0.4f

#define GCHUNKS  8                 // 8 x 38 = 304 >= 300 GT slots
#define GPERB    38                // GTs per block
#define NTHREADS 512               // 2 queries per thread
#define CAP      48                // per-GT candidate list capacity

// ---------------------------------------------------------------------------
// Single fused kernel, no workspace (d_ws re-poison costs ~39 us/replay).
//
// Round-10 post-mortem: __launch_bounds__(512, 8) clamped the allocator to
// 32 VGPR -> ~44 regs of live state spilled to scratch: WRITE_SIZE 1.8MB ->
// 33MB, FETCH 11->22.5MB, dur 50us. The STRUCTURE was fine; the pin was the
// bug. This round: identical kernel, plain __launch_bounds__(512). r7's
// same-sized state compiled to 44 VGPR (<64), which yields 8 waves/SIMD
// from ACTUAL usage -- occupancy without the clamp.
//
// Structure (consolidated from r5..r10 A/B series):
//   * >=8 waves/SIMD needed to hide the ~9-deep dependent FP chain;
//   * 1 pipelined broadcast ds_read_b128 per TWO register-resident tests;
//   * GT area computed in registers (no second LDS read);
//   * direct per-GT LDS atomic push (SALU branch, ~2% taken; proven in r5);
//   * NO #pragma unroll on the GT loop (r9 regression suspect).
//
// Phase 1 exact conservative prefilter: iou>0.4 <=> 3.5*inter > pa+ta,
// tested as fma(inter,3.5,-0.999pa) >= 0.999ta (0.1% margin >> f32 rounding
// => no true positive dropped; rare false positives in iou~[0.3997,0.4]
// removed by phase 2's exact math).
// Phase 2 (8 lanes/GT): exact reference-identical math (full IEEE div, same
// epsilon/op order, sigmoid), top-4 via u64 keys (valbits<<32)|~q ==
// (value desc, index asc) = jax.lax.top_k order; bitonic merge masks 1,2,4;
// zero-filler indices = smallest unused q. Validated absmax=0.0, rounds 3-10.
// ---------------------------------------------------------------------------
__global__ __launch_bounds__(NTHREADS) void fused_matcher(
    const float* __restrict__ logits,      // [B,Q,1]
    const float* __restrict__ pboxes,      // [B,Q,4]
    const float* __restrict__ tboxes,      // [B,G,4]
    float* __restrict__ out_vals,          // [B,G,K]
    float* __restrict__ out_idx,           // [B,G,K] (as float)
    float* __restrict__ out_mask)          // [B,G,K] (0/1 float)
{
    __shared__ float4 stb[GPERB + 1];                 // GT boxes (+sentinel)
    __shared__ unsigned scnt[GPERB];                  // per-GT counts
    __shared__ unsigned short sslot[GPERB][CAP];      // per-GT candidate q's

    const int b   = blockIdx.y;
    const int gc  = blockIdx.x;
    const int tid = threadIdx.x;
    const int g0  = gc * GPERB;
    const int ng  = (NG - g0 < GPERB) ? (NG - g0) : GPERB;

    const float4* __restrict__ tb4 =
        reinterpret_cast<const float4*>(tboxes) + (size_t)b * NG + g0;
    const float4* __restrict__ pb4 =
        reinterpret_cast<const float4*>(pboxes) + (size_t)b * NQ;

    // Dummy GT: zero area (ta999=0) and far corner => inter=0 with any real
    // query => test -qa999>=0 false. Dummy query: inverted far box => qa999
    // huge positive => never passes even vs dummy GT.
    const float4 dummyG = make_float4(2e9f, 2e9f, 2e9f, 2e9f);
    const float4 dummyQ = make_float4(2e9f, 2e9f, -2e9f, -2e9f);

    // ---- Stage: GT boxes to LDS; 2 query boxes to registers. ----
    if (tid < GPERB) {
        stb[tid]  = (tid < ng) ? tb4[tid] : dummyG;
        scnt[tid] = 0u;
    }
    if (tid == GPERB) stb[GPERB] = dummyG;

    float4 pA = pb4[tid];                                  // q = tid (<512)
    float4 pB = (NTHREADS + tid < NQ) ? pb4[NTHREADS + tid] : dummyQ;
    const float qaA = 0.999f * ((pA.z - pA.x) * (pA.w - pA.y));
    const float qaB = 0.999f * ((pB.z - pB.x) * (pB.w - pB.y));

    __syncthreads();

    // ---- Phase 1: 38 iterations, 1 pipelined broadcast b128 per 2 tests;
    //      GT area computed in registers (no second LDS read). ----
    float4 tc = stb[0];
    for (int gi = 0; gi < GPERB; ++gi) {
        float4 tn = stb[gi + 1];   // prefetch next GT box (broadcast read)
        const float ta999 = 0.999f * ((tc.z - tc.x) * (tc.w - tc.y));

#define TEST(P, QA, QIDX)                                                   \
        {                                                                   \
            float ltx = fmaxf(P.x, tc.x);                                   \
            float lty = fmaxf(P.y, tc.y);                                   \
            float rbx = fminf(P.z, tc.z);                                   \
            float rby = fminf(P.w, tc.w);                                   \
            float w = fmaxf(rbx - ltx, 0.0f);                               \
            float h = fmaxf(rby - lty, 0.0f);                               \
            float inter = w * h;                                            \
            if (fmaf(inter, 3.5f, -(QA)) >= ta999) {                        \
                unsigned pos = atomicAdd(&scnt[gi], 1u);                    \
                if (pos < CAP)                                              \
                    sslot[gi][pos] = (unsigned short)(QIDX);                \
            }                                                               \
        }
        TEST(pA, qaA, tid)
        TEST(pB, qaB, NTHREADS + tid)
#undef TEST
        tc = tn;
    }
    __syncthreads();

    // ---- Phase 2: exact select, 8 lanes per GT. ----
    const int grp = tid >> 3;    // GT within chunk (0..63)
    const int l8  = tid & 7;
    if (grp < ng) {
        const float4 tb = stb[grp];
        const float tarea = (tb.z - tb.x) * (tb.w - tb.y);
        int n = (int)scnt[grp];
        if (n > CAP) n = CAP;
        const float* __restrict__ lg = logits + (size_t)b * NQ;

        unsigned long long k0 = 0ull, k1 = 0ull, k2 = 0ull, k3 = 0ull;
        for (int i = l8; i < n; i += 8) {
            const int q = sslot[grp][i];
            const float4 pp = pb4[q];
            float parea = (pp.z - pp.x) * (pp.w - pp.y);
            float ltx = fmaxf(pp.x, tb.x);
            float lty = fmaxf(pp.y, tb.y);
            float rbx = fminf(pp.z, tb.z);
            float rby = fminf(pp.w, tb.w);
            float w = fmaxf(rbx - ltx, 0.0f);
            float h = fmaxf(rby - lty, 0.0f);
            float inter = w * h;
            float uni   = parea + tarea - inter;
            float iou   = inter / (uni + 1e-7f);
            if (iou > THRESH) {
                float x   = lg[q];
                float sc  = 1.0f / (1.0f + expf(-x));
                float val = sc * iou;
                unsigned long long ck =
                    ((unsigned long long)__float_as_uint(val) << 32) |
                    (unsigned long long)(unsigned)(~(unsigned)q);
                if (ck > k3) {
                    if (ck > k0)      { k3 = k2; k2 = k1; k1 = k0; k0 = ck; }
                    else if (ck > k1) { k3 = k2; k2 = k1; k1 = ck; }
                    else if (ck > k2) { k3 = k2; k2 = ck; }
                    else              { k3 = ck; }
                }
            }
        }

        // Bitonic merge of sorted-4 lists across the 8-lane group.
#define MERGE_STEP(MASK)                                                    \
        {                                                                   \
            unsigned long long p0 = __shfl_xor(k0, MASK, 64);               \
            unsigned long long p1 = __shfl_xor(k1, MASK, 64);               \
            unsigned long long p2 = __shfl_xor(k2, MASK, 64);               \
            unsigned long long p3 = __shfl_xor(k3, MASK, 64);               \
            k0 = k0 > p3 ? k0 : p3;                                         \
            k1 = k1 > p2 ? k1 : p2;                                         \
            k2 = k2 > p1 ? k2 : p1;                                         \
            k3 = k3 > p0 ? k3 : p0;                                         \
            unsigned long long t;                                           \
            if (k0 < k2) { t = k0; k0 = k2; k2 = t; }                       \
            if (k1 < k3) { t = k1; k1 = k3; k3 = t; }                       \
            if (k0 < k1) { t = k0; k0 = k1; k1 = t; }                       \
            if (k2 < k3) { t = k2; k2 = k3; k3 = t; }                       \
        }
        MERGE_STEP(1)
        MERGE_STEP(2)
        MERGE_STEP(4)
#undef MERGE_STEP

        if (l8 == 0) {
            const int iq0 = k0 ? (int)~(unsigned)k0 : -1;
            const int iq1 = k1 ? (int)~(unsigned)k1 : -1;
            const int iq2 = k2 ? (int)~(unsigned)k2 : -1;
            float4 vv, vi, vm;
            float* pv = &vv.x; float* pi_ = &vi.x; float* pm = &vm.x;
            int fill = 0;
#define EMIT(J, KJ)                                                         \
            {                                                               \
                if (KJ != 0ull) {                                           \
                    pv[J]  = __uint_as_float((unsigned)(KJ >> 32));         \
                    pi_[J] = (float)(int)~(unsigned)KJ;                     \
                    pm[J]  = 1.0f;                                          \
                } else {                                                    \
                    while (fill == iq0 || fill == iq1 || fill == iq2)       \
                        ++fill;                                             \
                    pv[J]  = 0.0f;                                          \
                    pi_[J] = (float)fill;                                   \
                    pm[J]  = 0.0f;                                          \
                    ++fill;                                                 \
                }                                                           \
            }
            EMIT(0, k0) EMIT(1, k1) EMIT(2, k2) EMIT(3, k3)
#undef EMIT
            const size_t o4 = (size_t)b * NG + g0 + grp;  // float4 index
            reinterpret_cast<float4*>(out_vals)[o4] = vv;
            reinterpret_cast<float4*>(out_idx)[o4]  = vi;
            reinterpret_cast<float4*>(out_mask)[o4] = vm;
        }
    }
}

extern "C" void kernel_launch(void* const* d_in, const int* in_sizes, int n_in,
                              void* d_out, int out_size, void* d_ws, size_t ws_size,
                              hipStream_t stream) {
    const float* logits = (const float*)d_in[0];  // [128,1000,1]
    const float* pboxes = (const float*)d_in[1];  // [128,1000,4]
    const float* tboxes = (const float*)d_in[2];  // [128,300,4]

    float* out = (float*)d_out;
    const size_t bgk = (size_t)NB * NG * NK;      // 153600
    float* out_vals = out;
    float* out_idx  = out + bgk;
    float* out_mask = out + 2 * bgk;

    dim3 grid(GCHUNKS, NB);                       // (8,128) = 1024 blocks
    fused_matcher<<<grid, NTHREADS, 0, stream>>>(logits, pboxes, tboxes,
                                                 out_vals, out_idx, out_mask);
}

// Round 12
// 43.521 us; speedup vs baseline: 1.1498x; 1.1498x over previous
//
#include <hip/hip_runtime.h>

#define NB 128
#define NQ 1000
#define NG 300
#define NK 4
#define THRESH 0.4f

#define GCHUNKS  16                // 16 x 19 = 304 >= 300 GT slots
#define GPERB    19                // GTs per block
#define NTHREADS 256               // 4 queries per thread
#define NWAVES   4
#define CAPW     24                // per-(GT,wave) slot capacity
#define SLOTS    (GPERB * NWAVES * CAPW)   // 1824 u16

// ---------------------------------------------------------------------------
// Single fused kernel, no workspace (d_ws re-poison costs ~39 us/replay).
//
// Round-11 post-mortem: the wave-uniform `if(pass) atomicAdd(&scnt[gi])`
// site is expanded by LLVM's atomic optimizer (ballot+mbcnt+one-lane
// ds_add_rtn+readfirstlane, ~16 instr/event) AND its returned value puts a
// ~120cyc LDS round-trip on the wave critical path ~40% of iterations ->
// VALUBusy 50% with 50% stall. Fix: hand-rolled wave aggregation with NO
// atomic and NO return dependency. Each GT is visited once per wave, so
// per-(GT,wave) lists need no counter: rank = popc(ballot & below_lanes),
// region is private to (gi,wave), writes are fire-and-forget ds_write_b16,
// lists are sentinel-initialized (0xFFFF) and phase 2 scans the fixed
// region. The only loop LDS read is the 1-ahead pipelined broadcast GT box,
// amortized over 4 register-resident tests. 32 waves/CU from actual VGPR
// usage (no __launch_bounds__ min-waves pin -- r10 spill lesson). No
// #pragma unroll of the GT loop beyond 1 (r9 lesson).
//
// Phase 1 exact conservative prefilter: iou>0.4 <=> 3.5*inter > pa+ta,
// tested as fma(inter,3.5,-0.999pa) >= 0.999ta (0.1% margin >> f32 rounding
// => no true positive dropped; rare false positives in iou~[0.3997,0.4]
// removed by phase 2's exact math).
// Phase 2 (8 lanes/GT): exact reference-identical math (full IEEE div, same
// epsilon/op order, sigmoid), top-4 via u64 keys (valbits<<32)|~q ==
// (value desc, index asc) = jax.lax.top_k order; bitonic merge masks 1,2,4;
// zero-filler indices = smallest unused q. Validated absmax=0.0, rounds 3-11.
// ---------------------------------------------------------------------------
__global__ __launch_bounds__(NTHREADS) void fused_matcher(
    const float* __restrict__ logits,      // [B,Q,1]
    const float* __restrict__ pboxes,      // [B,Q,4]
    const float* __restrict__ tboxes,      // [B,G,4]
    float* __restrict__ out_vals,          // [B,G,K]
    float* __restrict__ out_idx,           // [B,G,K] (as float)
    float* __restrict__ out_mask)          // [B,G,K] (0/1 float)
{
    __shared__ float4 stb[GPERB + 1];           // GT boxes (+sentinel)
    __shared__ unsigned short sslot[SLOTS];     // [gi][wave][CAPW] candidates

    const int b    = blockIdx.y;
    const int gc   = blockIdx.x;
    const int tid  = threadIdx.x;
    const int lane = tid & 63;
    const int wv   = tid >> 6;                  // wave id 0..3
    const int g0   = gc * GPERB;
    const int ng   = (NG - g0 < GPERB) ? (NG - g0) : GPERB;

    const float4* __restrict__ tb4 =
        reinterpret_cast<const float4*>(tboxes) + (size_t)b * NG + g0;
    const float4* __restrict__ pb4 =
        reinterpret_cast<const float4*>(pboxes) + (size_t)b * NQ;

    // Dummy GT: zero area + far corner => inter=0, ta999=0 => test
    // -qa999 >= 0 false for all real queries. Dummy query: inverted far box
    // => qa999 huge positive => never passes any GT (incl. dummy GT).
    const float4 dummyG = make_float4(2e9f, 2e9f, 2e9f, 2e9f);
    const float4 dummyQ = make_float4(2e9f, 2e9f, -2e9f, -2e9f);

    // ---- Stage: GT boxes; sentinel-init slot lists; 4 query boxes. ----
    if (tid <= GPERB) stb[tid] = (tid < ng) ? tb4[tid] : dummyG;

    unsigned* s32 = reinterpret_cast<unsigned*>(sslot);
    for (int i = tid; i < SLOTS / 2; i += NTHREADS) s32[i] = 0xFFFFFFFFu;

    float4 pA = pb4[tid];
    float4 pB = pb4[NTHREADS + tid];
    float4 pC = pb4[2 * NTHREADS + tid];
    float4 pD = (3 * NTHREADS + tid < NQ) ? pb4[3 * NTHREADS + tid] : dummyQ;
    const float qaA = 0.999f * ((pA.z - pA.x) * (pA.w - pA.y));
    const float qaB = 0.999f * ((pB.z - pB.x) * (pB.w - pB.y));
    const float qaC = 0.999f * ((pC.z - pC.x) * (pC.w - pC.y));
    const float qaD = 0.999f * ((pD.z - pD.x) * (pD.w - pD.y));

    const unsigned long long lt = (1ull << lane) - 1ull;

    __syncthreads();

    // ---- Phase 1: 19 iterations; 1 pipelined broadcast b128 per 4 tests;
    //      ballot-ranked fire-and-forget pushes, no atomics. ----
    float4 tc = stb[0];
#pragma unroll 1
    for (int gi = 0; gi < GPERB; ++gi) {
        float4 tn = stb[gi + 1];   // prefetch next GT box (broadcast read)
        const float ta999 = 0.999f * ((tc.z - tc.x) * (tc.w - tc.y));
        unsigned short* row = &sslot[(gi * NWAVES + wv) * CAPW];
        int base = 0;

#define TEST(P, QA, QIDX)                                                   \
        {                                                                   \
            float ltx = fmaxf(P.x, tc.x);                                   \
            float lty = fmaxf(P.y, tc.y);                                   \
            float rbx = fminf(P.z, tc.z);                                   \
            float rby = fminf(P.w, tc.w);                                   \
            float w = fmaxf(rbx - ltx, 0.0f);                               \
            float h = fmaxf(rby - lty, 0.0f);                               \
            float inter = w * h;                                            \
            bool pass = fmaf(inter, 3.5f, -(QA)) >= ta999;                  \
            unsigned long long m = __ballot(pass);                          \
            if (pass) {                                                     \
                int r = base + __popcll(m & lt);                            \
                if (r < CAPW) row[r] = (unsigned short)(QIDX);              \
            }                                                               \
            base += __popcll(m);                                            \
        }
        TEST(pA, qaA, tid)
        TEST(pB, qaB, NTHREADS + tid)
        TEST(pC, qaC, 2 * NTHREADS + tid)
        TEST(pD, qaD, 3 * NTHREADS + tid)
#undef TEST
        tc = tn;
    }
    __syncthreads();

    // ---- Phase 2: exact select, 8 lanes per GT, sentinel-scan lists. ----
    const int grp = tid >> 3;    // GT within chunk (0..31)
    const int l8  = tid & 7;
    if (grp < ng) {
        const float4 tb = stb[grp];
        const float tarea = (tb.z - tb.x) * (tb.w - tb.y);
        const float* __restrict__ lg = logits + (size_t)b * NQ;
        const unsigned short* reg = &sslot[grp * (NWAVES * CAPW)];

        unsigned long long k0 = 0ull, k1 = 0ull, k2 = 0ull, k3 = 0ull;
        for (int i = l8; i < NWAVES * CAPW; i += 8) {
            const int q = reg[i];
            if (q == 0xFFFF) continue;
            const float4 pp = pb4[q];
            float parea = (pp.z - pp.x) * (pp.w - pp.y);
            float ltx = fmaxf(pp.x, tb.x);
            float lty = fmaxf(pp.y, tb.y);
            float rbx = fminf(pp.z, tb.z);
            float rby = fminf(pp.w, tb.w);
            float w = fmaxf(rbx - ltx, 0.0f);
            float h = fmaxf(rby - lty, 0.0f);
            float inter = w * h;
            float uni   = parea + tarea - inter;
            float iou   = inter / (uni + 1e-7f);
            if (iou > THRESH) {
                float x   = lg[q];
                float sc  = 1.0f / (1.0f + expf(-x));
                float val = sc * iou;
                unsigned long long ck =
                    ((unsigned long long)__float_as_uint(val) << 32) |
                    (unsigned long long)(unsigned)(~(unsigned)q);
                if (ck > k3) {
                    if (ck > k0)      { k3 = k2; k2 = k1; k1 = k0; k0 = ck; }
                    else if (ck > k1) { k3 = k2; k2 = k1; k1 = ck; }
                    else if (ck > k2) { k3 = k2; k2 = ck; }
                    else              { k3 = ck; }
                }
            }
        }

        // Bitonic merge of sorted-4 lists across the 8-lane group.
#define MERGE_STEP(MASK)                                                    \
        {                                                                   \
            unsigned long long p0 = __shfl_xor(k0, MASK, 64);               \
            unsigned long long p1 = __shfl_xor(k1, MASK, 64);               \
            unsigned long long p2 = __shfl_xor(k2, MASK, 64);               \
            unsigned long long p3 = __shfl_xor(k3, MASK, 64);               \
            k0 = k0 > p3 ? k0 : p3;                                         \
            k1 = k1 > p2 ? k1 : p2;                                         \
            k2 = k2 > p1 ? k2 : p1;                                         \
            k3 = k3 > p0 ? k3 : p0;                                         \
            unsigned long long t;                                           \
            if (k0 < k2) { t = k0; k0 = k2; k2 = t; }                       \
            if (k1 < k3) { t = k1; k1 = k3; k3 = t; }                       \
            if (k0 < k1) { t = k0; k0 = k1; k1 = t; }                       \
            if (k2 < k3) { t = k2; k2 = k3; k3 = t; }                       \
        }
        MERGE_STEP(1)
        MERGE_STEP(2)
        MERGE_STEP(4)
#undef MERGE_STEP

        if (l8 == 0) {
            const int iq0 = k0 ? (int)~(unsigned)k0 : -1;
            const int iq1 = k1 ? (int)~(unsigned)k1 : -1;
            const int iq2 = k2 ? (int)~(unsigned)k2 : -1;
            float4 vv, vi, vm;
            float* pv = &vv.x; float* pi_ = &vi.x; float* pm = &vm.x;
            int fill = 0;
#define EMIT(J, KJ)                                                         \
            {                                                               \
                if (KJ != 0ull) {                                           \
                    pv[J]  = __uint_as_float((unsigned)(KJ >> 32));         \
                    pi_[J] = (float)(int)~(unsigned)KJ;                     \
                    pm[J]  = 1.0f;                                          \
                } else {                                                    \
                    while (fill == iq0 || fill == iq1 || fill == iq2)       \
                        ++fill;                                             \
                    pv[J]  = 0.0f;                                          \
                    pi_[J] = (float)fill;                                   \
                    pm[J]  = 0.0f;                                          \
                    ++fill;                                                 \
                }                                                           \
            }
            EMIT(0, k0) EMIT(1, k1) EMIT(2, k2) EMIT(3, k3)
#undef EMIT
            const size_t o4 = (size_t)b * NG + g0 + grp;  // float4 index
            reinterpret_cast<float4*>(out_vals)[o4] = vv;
            reinterpret_cast<float4*>(out_idx)[o4]  = vi;
            reinterpret_cast<float4*>(out_mask)[o4] = vm;
        }
    }
}

extern "C" void kernel_launch(void* const* d_in, const int* in_sizes, int n_in,
                              void* d_out, int out_size, void* d_ws, size_t ws_size,
                              hipStream_t stream) {
    const float* logits = (const float*)d_in[0];  // [128,1000,1]
    const float* pboxes = (const float*)d_in[1];  // [128,1000,4]
    const float* tboxes = (const float*)d_in[2];  // [128,300,4]

    float* out = (float*)d_out;
    const size_t bgk = (size_t)NB * NG * NK;      // 153600
    float* out_vals = out;
    float* out_idx  = out + bgk;
    float* out_mask = out + 2 * bgk;

    dim3 grid(GCHUNKS, NB);                       // (16,128) = 2048 blocks
    fused_matcher<<<grid, NTHREADS, 0, stream>>>(logits, pboxes, tboxes,
                                                 out_vals, out_idx, out_mask);
}